// Round 11
// baseline (261.101 us; speedup 1.0000x reference)
//
#include <hip/hip_runtime.h>

// MultiHeadSelfAttention: B=4, S=2048, D=1024, H=16, HD=64, causal. fp32 I/O, bf16 MFMA.
// R19 = R18 prep/attn + RING GEMM (4-slot, fine per-phase interleave, counted vmcnt).
// R18 datum: gap ~3us/launch -> kernel-sum ~246, GEMMs ~150us (~690 TF). All prior
// structures bunched ds_reads/stages per K-tile (m196 anti-pattern). This kernel:
//   BK=32; slot = A 256x32 + B BNx32; 4-slot ring staged 2 K-STEPS AHEAD (4-6 phase
//   lead ~1400cy > 900cy HBM latency -> counted waits never stall on fresh loads).
//   Per K-step 2 phases: {4-8 ds_read_b128 -> 2 global_load_lds -> barrier -> setprio
//   + MFMA cluster -> setprio -> [vmcnt(LPK) once/K-step] -> barrier}. Trailing
//   barrier AFTER vmcnt makes per-wave counters collective (required: slot data is
//   staged by ALL waves). B-frags register-held across the phase pair.
//   Ledger (per wave, LPK loads/K-step): end of t, outstanding = K(t+1)+K(t+2) = 2*LPK;
//   vmcnt(LPK) -> K(t+1) landed. Tail t>=nk-2: vmcnt(0) (those loads 2-4 phases old).
//   Swizzle: R17-proven both-sides granule XOR g^((row>>1)&3) (bank-verified, conflict
//   0 measured R15). XCD-bijective block swizzle. QKV 256x256 grid 384; OUT 256x128
//   grid 256 (one full round). attn = R14 1024-block balanced (81us proven).

typedef short s16;
typedef __attribute__((ext_vector_type(4))) short s16x4;
typedef __attribute__((ext_vector_type(8))) short bf16x8;
typedef __attribute__((ext_vector_type(4))) float f32x4;

__device__ __forceinline__ s16 f2bf(float f) {
    union { float f; unsigned int i; } v;
    v.f = f;
    unsigned int r = v.i + 0x7fffu + ((v.i >> 16) & 1u);  // RNE
    return (s16)(r >> 16);
}

// pack two fp32 -> bf16x2 dword (round-half-up)
__device__ __forceinline__ unsigned pack_bf16(float a, float b) {
    union { float f; unsigned u; } x, y;
    x.f = a; y.f = b;
    return __byte_perm(x.u + 0x8000u, y.u + 0x8000u, 0x7632);
}

__device__ __forceinline__ void load_lds16(const s16* g, s16* lds_base) {
    __builtin_amdgcn_global_load_lds(
        (const __attribute__((address_space(1))) void*)g,
        (__attribute__((address_space(3))) void*)lds_base, 16, 0, 0);
}

template <int N>
__device__ __forceinline__ void waitcnt_vm() {
    if constexpr (N == 0)      asm volatile("s_waitcnt vmcnt(0)" ::: "memory");
    else if constexpr (N == 3) asm volatile("s_waitcnt vmcnt(3)" ::: "memory");
    else if constexpr (N == 4) asm volatile("s_waitcnt vmcnt(4)" ::: "memory");
}

// ---------------------------------------------------------------------------
// Fused prep: cast x (blocks 0..8191), transpose Wqkv (8192..11263, 96x32),
// transpose Wout (11264..12287, 32x32). (R18-proven)
// ---------------------------------------------------------------------------
__global__ __launch_bounds__(256) void prep(
    const float* __restrict__ x,    s16* __restrict__ xo,
    const float* __restrict__ Wq,   s16* __restrict__ oq,
    const float* __restrict__ Wo,   s16* __restrict__ oo) {
    const int bid = blockIdx.x;
    const int tid = threadIdx.x;
    if (bid < 8192) {
        const int i = (bid * 256 + tid) * 4;
        const float4 f = *(const float4*)(x + i);
        s16x4 r = {f2bf(f.x), f2bf(f.y), f2bf(f.z), f2bf(f.w)};
        *(s16x4*)(xo + i) = r;
        return;
    }
    __shared__ float tile[32][33];
    const float* in;
    s16* out;
    int C, bx, by;
    if (bid < 11264) {
        const int b = bid - 8192;
        in = Wq; out = oq; C = 3072; bx = b % 96; by = b / 96;
    } else {
        const int b = bid - 11264;
        in = Wo; out = oo; C = 1024; bx = b & 31; by = b >> 5;
    }
    const int R = 1024;
    const int cb = bx * 32, rb = by * 32;
    const int tx = tid & 31, ty = tid >> 5;  // 32 x 8
#pragma unroll
    for (int i = 0; i < 32; i += 8)
        tile[ty + i][tx] = in[(size_t)(rb + ty + i) * C + cb + tx];
    __syncthreads();
#pragma unroll
    for (int i = 0; i < 32; i += 8)
        out[(size_t)(cb + ty + i) * R + rb + tx] = f2bf(tile[tx][ty + i]);
}

// ---------------------------------------------------------------------------
// C[M,N] = A[M,K] @ Bt[N,K]^T + bias[N]. A,Bt bf16; C fp32 or bf16.
// 4-slot ring, BK=32, BM=256, BN=BCH*128; 8 waves 2Mx4N, wave out 128x(BCH*32).
// Requires M%256==0, N%BN==0, K%128==0, grid=(M/256)*(N/BN), grid%8==0.
// ---------------------------------------------------------------------------
template <bool OUT_F32, int BCH>
__global__ __launch_bounds__(512, 2) void gemm_ring(
    const s16* __restrict__ A,
    const s16* __restrict__ Bt,
    const float* __restrict__ bias,
    void* __restrict__ Cv,
    int M, int N, int K, int gx) {
    constexpr int BN    = BCH * 128;
    constexpr int NF    = BCH * 2;       // B frags per wave (16-col units)
    constexpr int LPK   = 2 + BCH;       // loads/thread/K-step
    constexpr int ASLOT = 256 * 32;      // s16 per A slot
    constexpr int BSLOT = BN * 32;
    __shared__ __attribute__((aligned(16))) s16 As[4 * ASLOT];
    __shared__ __attribute__((aligned(16))) s16 Bs[4 * BSLOT];

    const int tid  = threadIdx.x;
    const int lane = tid & 63;
    const int wave = tid >> 6;           // 0..7
    const int l15  = lane & 15;
    const int quad = lane >> 4;
    const int wr   = wave >> 2;          // 0..1 (M half, 128 rows)
    const int wc   = wave & 3;           // 0..3 (N quarter, NF*16 cols)

    // XCD-bijective swizzle (grid % 8 == 0)
    const int cpx = (int)gridDim.x >> 3;
    const int bid = (int)blockIdx.x;
    const int swz = (bid & 7) * cpx + (bid >> 3);
    const int m0 = (swz / gx) * 256;
    const int n0 = (swz % gx) * BN;

    // staging map: thread = (row sr of a 128-row chunk, granule gl);
    // source granule pre-swizzled gl^((sr>>1)&3); LDS dest linear (both-sides rule).
    const int sr  = tid >> 2;            // 0..127
    const int gl  = tid & 3;
    const int gsw = gl ^ ((sr >> 1) & 3);
    const s16* Ag = A  + (size_t)(m0 + sr) * K + gsw * 8;
    const s16* Bg = Bt + (size_t)(n0 + sr) * K + gsw * 8;

    auto stgA = [&](int slot, int kt) {
        load_lds16(Ag + (size_t)kt * 32,           &As[slot * ASLOT + wave * 512]);
        load_lds16(Ag + (size_t)128 * K + kt * 32, &As[slot * ASLOT + 4096 + wave * 512]);
    };
    auto stgB = [&](int slot, int kt) {
        load_lds16(Bg + (size_t)kt * 32, &Bs[slot * BSLOT + wave * 512]);
        if constexpr (BCH == 2)
            load_lds16(Bg + (size_t)128 * K + kt * 32, &Bs[slot * BSLOT + 4096 + wave * 512]);
    };

    f32x4 acc[8][NF];
#pragma unroll
    for (int i = 0; i < 8; ++i)
#pragma unroll
        for (int j = 0; j < NF; ++j)
            acc[i][j] = (f32x4){0.f, 0.f, 0.f, 0.f};

    const int nk = K >> 5;               // BK=32 steps (even; >=4)
    const int gr = ((quad ^ ((l15 >> 1) & 3)) << 3);  // swizzled read granule (s16)

    // prologue: stage K0->slot0, K1->slot1; wait K0 (K1 stays in flight)
    stgA(0, 0); stgB(0, 0);
    stgA(1, 1); stgB(1, 1);
    waitcnt_vm<LPK>();
    __builtin_amdgcn_s_barrier();

    for (int tq = 0; tq < nk; tq += 4) {
#pragma unroll
        for (int u = 0; u < 4; ++u) {
            const int t = tq + u;
            const s16* Ab = As + u * ASLOT;          // slot = t&3 = u
            const s16* Bb = Bs + u * BSLOT;
            const bool pre = (t + 2 < nk);
            const int ns = (t + 2) & 3;

            // ---- phase even: A m-frags 0..3 + all B frags; stage next-next A ----
            bf16x8 bf[NF], af[4];
#pragma unroll
            for (int nf = 0; nf < NF; ++nf)
                bf[nf] = *(const bf16x8*)(Bb + (wc * (NF * 16) + nf * 16 + l15) * 32 + gr);
#pragma unroll
            for (int mf = 0; mf < 4; ++mf)
                af[mf] = *(const bf16x8*)(Ab + (wr * 128 + mf * 16 + l15) * 32 + gr);
            if (pre) stgA(ns, t + 2);
            __builtin_amdgcn_s_barrier();
            __builtin_amdgcn_s_setprio(1);
#pragma unroll
            for (int mf = 0; mf < 4; ++mf)
#pragma unroll
                for (int nf = 0; nf < NF; ++nf)
                    acc[mf][nf] = __builtin_amdgcn_mfma_f32_16x16x32_bf16(
                        af[mf], bf[nf], acc[mf][nf], 0, 0, 0);
            __builtin_amdgcn_s_setprio(0);
            __builtin_amdgcn_s_barrier();

            // ---- phase odd: A m-frags 4..7 (B held); stage next-next B ----
#pragma unroll
            for (int mf = 0; mf < 4; ++mf)
                af[mf] = *(const bf16x8*)(Ab + (wr * 128 + (mf + 4) * 16 + l15) * 32 + gr);
            if (pre) stgB(ns, t + 2);
            __builtin_amdgcn_s_barrier();
            __builtin_amdgcn_s_setprio(1);
#pragma unroll
            for (int mf = 0; mf < 4; ++mf)
#pragma unroll
                for (int nf = 0; nf < NF; ++nf)
                    acc[mf + 4][nf] = __builtin_amdgcn_mfma_f32_16x16x32_bf16(
                        af[mf], bf[nf], acc[mf + 4][nf], 0, 0, 0);
            __builtin_amdgcn_s_setprio(0);
            // once per K-step: free K(t+1) (issued a full K-step ago); tail drains
            if (t < nk - 2)      waitcnt_vm<LPK>();
            else if (t == nk - 2) waitcnt_vm<0>();
            __builtin_amdgcn_s_barrier();  // collective: all waves' loads landed
        }
    }

    // epilogue: row-contiguous stores
    float bv[NF];
#pragma unroll
    for (int nf = 0; nf < NF; ++nf)
        bv[nf] = bias[n0 + wc * (NF * 16) + nf * 16 + l15];
#pragma unroll
    for (int mf = 0; mf < 8; ++mf) {
#pragma unroll
        for (int r = 0; r < 4; ++r) {
            const int row = m0 + wr * 128 + mf * 16 + quad * 4 + r;
#pragma unroll
            for (int nf = 0; nf < NF; ++nf) {
                const int col = n0 + wc * (NF * 16) + nf * 16 + l15;
                const float v = acc[mf][nf][r] + bv[nf];
                if constexpr (OUT_F32)
                    ((float*)Cv)[(size_t)row * N + col] = v;
                else
                    ((s16*)Cv)[(size_t)row * N + col] = f2bf(v);
            }
        }
    }
}

// ---------------------------------------------------------------------------
// Flash attention (causal), fixed-M softmax, S^T formulation. (R14/R16/R17 proven)
// Flat grid of 1024 blocks = 4/CU resident. bid bits: hi=bid>>8 (CU-sharing round),
// bh=(bid>>2)&63, a=bid&3; qt = hi&1 ? 15-(2a+(hi>>1)) : 2a+(hi>>1).
// -> per-CU qt sets {x, 15-x, x+1, 14-x}: exactly 68 key-tile units per CU.
// ---------------------------------------------------------------------------
__global__ __launch_bounds__(256) void attn_fwd(
    const s16* __restrict__ qkv,
    s16* __restrict__ attn) {
    __shared__ __attribute__((aligned(16))) s16 Ks[64 * 72];
    __shared__ __attribute__((aligned(16))) s16 Vt[64 * 72];
    __shared__ __attribute__((aligned(16))) s16 PT[4][32][88];

    const int tid  = threadIdx.x;
    const int lane = tid & 63;
    const int wave = tid >> 6;
    const int l15  = lane & 15;
    const int quad = lane >> 4;

    // balanced (bh, qt) decomposition (see header comment)
    const int bid = blockIdx.x;
    const int hi  = bid >> 8;
    const int a   = bid & 3;
    const int bh  = (bid >> 2) & 63;
    const int qbase = a * 2 + (hi >> 1);
    const int qt  = (hi & 1) ? 15 - qbase : qbase;

    const size_t rowbase = (size_t)(bh >> 4) * 2048;
    const int hoff = (bh & 15) * 64;
    const int kp  = tid >> 3;  // 0..31: staged key-pair {2kp, 2kp+1}
    const int p_s = tid & 7;   // hd granule
    const int kg  = kp >> 2;   // key granule of this thread's pair

    const float C2 = 0.18033688011112042f;  // 0.125 * log2(e)
    const float M2 = 12.0f;                 // fixed shift (softmax shift-invariant)

    const int wq = qt * 128 + wave * 32;

    // Q fragments: lane holds Q[q = wq + qs*16 + l15][d = ks*32 + quad*8 + j]
    bf16x8 qf[2][2];
#pragma unroll
    for (int qs = 0; qs < 2; ++qs)
#pragma unroll
        for (int ks = 0; ks < 2; ++ks)
            qf[qs][ks] = *(const bf16x8*)(qkv + (rowbase + wq + qs * 16 + l15) * 3072 + hoff + ks * 32 + quad * 8);

    float l_lane[2] = {0.f, 0.f};
    f32x4 o[2][4];  // [qs][hs]; C-layout: q-col = l15, hd-row = hs*16 + quad*4 + r
#pragma unroll
    for (int qs = 0; qs < 2; ++qs)
#pragma unroll
        for (int hs = 0; hs < 4; ++hs)
            o[qs][hs] = (f32x4){0.f, 0.f, 0.f, 0.f};

    const int nkt = qt * 2 + 2;
    // prefetch tile 0 K/V
    bf16x8 kv[2], vv[2];
#pragma unroll
    for (int dk = 0; dk < 2; ++dk) {
        const s16* g = qkv + (rowbase + 2 * kp + dk) * 3072 + hoff + p_s * 8;
        kv[dk] = *(const bf16x8*)(g + 1024);
        vv[dk] = *(const bf16x8*)(g + 2048);
    }

    for (int kt = 0; kt < nkt; ++kt) {
        const int k0 = kt * 64;
        __syncthreads();  // prev iteration's LDS reads done
#pragma unroll
        for (int dk = 0; dk < 2; ++dk)  // K natural layout (R5-proven)
            *(bf16x8*)(Ks + (2 * kp + dk) * 72 + p_s * 8) = kv[dk];
#pragma unroll
        for (int j = 0; j < 8; ++j) {   // V^T swizzled, key-pair b32 (R7-verified)
            const unsigned dw = (unsigned)(unsigned short)vv[0][j] |
                                ((unsigned)(unsigned short)vv[1][j] << 16);
            *(unsigned*)(Vt + (p_s * 8 + j) * 72 + ((kg ^ p_s) << 3) + (2 * kp & 7)) = dw;
        }
        __syncthreads();

        if (kt + 1 < nkt) {  // prefetch next tile under compute
#pragma unroll
            for (int dk = 0; dk < 2; ++dk) {
                const s16* g = qkv + (rowbase + k0 + 64 + 2 * kp + dk) * 3072 + hoff + p_s * 8;
                kv[dk] = *(const bf16x8*)(g + 1024);
                vv[dk] = *(const bf16x8*)(g + 2048);
            }
        }

        if (k0 > wq + 31) continue;  // fully masked for this wave

        // S^T = K Q^T : st[qs][kb], key subtiles kb of 16
        f32x4 st[2][4];
#pragma unroll
        for (int qs = 0; qs < 2; ++qs)
#pragma unroll
            for (int kb = 0; kb < 4; ++kb)
                st[qs][kb] = (f32x4){0.f, 0.f, 0.f, 0.f};
        __builtin_amdgcn_s_setprio(1);
#pragma unroll
        for (int kb = 0; kb < 4; ++kb)
#pragma unroll
            for (int ks = 0; ks < 2; ++ks) {
                const bf16x8 kf = *(const bf16x8*)(Ks + (kb * 16 + l15) * 72 + ks * 32 + quad * 8);
#pragma unroll
                for (int qs = 0; qs < 2; ++qs)
                    st[qs][kb] = __builtin_amdgcn_mfma_f32_16x16x32_bf16(kf, qf[qs][ks], st[qs][kb], 0, 0, 0);
            }
        __builtin_amdgcn_s_setprio(0);

        // softmax (fixed-M) + P^T -> PT (b64, conflict-free)
        const bool edge = (k0 + 63 > wq);
#pragma unroll
        for (int qs = 0; qs < 2; ++qs) {
            const int q = wq + qs * 16 + l15;
#pragma unroll
            for (int kb = 0; kb < 4; ++kb) {
                float p4[4];
#pragma unroll
                for (int r = 0; r < 4; ++r) {
                    float t = fmaf(st[qs][kb][r], C2, -M2);
                    if (edge) {
                        const int key = k0 + kb * 16 + quad * 4 + r;
                        t = (key <= q) ? t : -150.f;  // exp2(-150) == 0
                    }
                    p4[r] = __builtin_amdgcn_exp2f(t);
                    l_lane[qs] += p4[r];
                }
                uint2 dd;
                dd.x = pack_bf16(p4[0], p4[1]);
                dd.y = pack_bf16(p4[2], p4[3]);
                *(uint2*)(&PT[wave][qs * 16 + l15][kb * 16 + quad * 4]) = dd;
            }
        }

        // O^T += V^T P^T
        __builtin_amdgcn_s_setprio(1);
#pragma unroll
        for (int kk = 0; kk < 2; ++kk) {
            bf16x8 pf[2];
#pragma unroll
            for (int qs = 0; qs < 2; ++qs)
                pf[qs] = *(const bf16x8*)(&PT[wave][qs * 16 + l15][kk * 32 + quad * 8]);
#pragma unroll
            for (int hs = 0; hs < 4; ++hs) {
                const bf16x8 vf = *(const bf16x8*)(
                    Vt + (hs * 16 + l15) * 72 + (((kk * 4 + quad) ^ (2 * hs + (l15 >> 3))) << 3));
#pragma unroll
                for (int qs = 0; qs < 2; ++qs)
                    o[qs][hs] = __builtin_amdgcn_mfma_f32_16x16x32_bf16(vf, pf[qs], o[qs][hs], 0, 0, 0);
            }
        }
        __builtin_amdgcn_s_setprio(0);
    }

    // l: sum across the 4 quads (lanes with same l15)
    float rl[2];
#pragma unroll
    for (int qs = 0; qs < 2; ++qs) {
        float l = l_lane[qs];
        l += __shfl_xor(l, 16);
        l += __shfl_xor(l, 32);
        rl[qs] = 1.f / l;
    }

    // epilogue: O^T[hd][q] -> attn[q][hoff+hd]; 4 consecutive hd per reg-quad -> b64
#pragma unroll
    for (int qs = 0; qs < 2; ++qs) {
        const int q = wq + qs * 16 + l15;
#pragma unroll
        for (int hs = 0; hs < 4; ++hs) {
            uint2 dd;
            dd.x = pack_bf16(o[qs][hs][0] * rl[qs], o[qs][hs][1] * rl[qs]);
            dd.y = pack_bf16(o[qs][hs][2] * rl[qs], o[qs][hs][3] * rl[qs]);
            *(uint2*)(attn + (rowbase + q) * 1024 + hoff + hs * 16 + quad * 4) = dd;
        }
    }
}

// ---------------------------------------------------------------------------
extern "C" void kernel_launch(void* const* d_in, const int* in_sizes, int n_in,
                              void* d_out, int out_size, void* d_ws, size_t ws_size,
                              hipStream_t stream) {
    const float* x    = (const float*)d_in[0];  // [8192,1024]
    const float* Wqkv = (const float*)d_in[1];  // [1024,3072]
    const float* bqkv = (const float*)d_in[2];  // [3072]
    const float* Wout = (const float*)d_in[3];  // [1024,1024]
    const float* bout = (const float*)d_in[4];  // [1024]
    float* out = (float*)d_out;                 // [8192,1024] fp32

    s16* ws   = (s16*)d_ws;
    s16* qkv  = ws;                          // [8192,3072] bf16
    s16* xba  = qkv + (size_t)8192 * 3072;   // [8192,1024] bf16: x-cast, later attn output
    s16* wtq  = xba + (size_t)8192 * 1024;   // [3072,1024] bf16
    s16* wto  = wtq + (size_t)3072 * 1024;   // [1024,1024] bf16

    prep<<<12288, 256, 0, stream>>>(x, xba, Wqkv, wtq, Wout, wto);
    // QKV: 256x256 tile, grid (3072/256)x(8192/256) = 12x32 = 384 blocks
    gemm_ring<false, 2><<<384, 512, 0, stream>>>(
        xba, wtq, bqkv, qkv, 8192, 3072, 1024, 12);
    attn_fwd<<<1024, 256, 0, stream>>>(qkv, xba);  // xba dead; reused as attn buf
    // OUT: 256x128 tile, grid (1024/128)x(8192/256) = 8x32 = 256 blocks (one round)
    gemm_ring<true, 1><<<256, 512, 0, stream>>>(
        xba, wto, bout, out, 8192, 1024, 1024, 8);
}